// Round 3
// baseline (227.167 us; speedup 1.0000x reference)
//
#include <hip/hip_runtime.h>
#include <math.h>

#define N_NODES 50000
#define N_EDGES 800000
#define D_FEAT 128
#define HIDDEN 256
#define NB_SCAN 196           // ceil(50000/256)
#define GEMM_BLOCKS 782       // ceil(50000/64)

#define AGG_B 2048            // 8192 waves

#define NSLICE 32             // edge slices for CSR build
#define SLICE_E 25000         // 800000 / 32
#define NPART 2               // node partitions for hist tasks
#define PART_N 25000          // 50000 / 2
#define NTASK 64              // NSLICE * NPART

#define CVT_B 512             // cvt/Wfrag blocks in prep_hist
#define PH_B (NTASK + CVT_B)  // prep_hist grid
#define SCAT_B 3125           // 800000/256 edge-parallel scatter

typedef __bf16 bf16x8 __attribute__((ext_vector_type(8)));
typedef float f32x4 __attribute__((ext_vector_type(4)));

__device__ __forceinline__ unsigned f2b(float f) {
    unsigned u = __builtin_bit_cast(unsigned, f);
    return (u + 0x7fff + ((u >> 16) & 1)) >> 16;  // RNE, low 16 bits valid
}

// ---------- fused: per-(slice,part) histogram + rank | cvt_x | build_wfrag ----
// blocks 0..63: hist task (slice = b>>1, part = b&1), 50 KB LDS u16-packed.
//   Records rank[e] = prior count in this edge's (slice,dst) bucket.
// blocks 64..575: x -> bf16-packed xb, and W1l|W1r -> MFMA-layout Wfrag.
__global__ __launch_bounds__(256) void prep_hist(
    const float* __restrict__ x, const int* __restrict__ dst,
    const float* __restrict__ W1l, const float* __restrict__ W1r,
    unsigned* __restrict__ arr, unsigned short* __restrict__ rank,
    unsigned* __restrict__ xb, unsigned short* __restrict__ Wfrag) {
    __shared__ unsigned hist[PART_N / 2 + 8];   // 12508 u32 = ~50 KB
    int b = blockIdx.x;
    int t = threadIdx.x;
    if (b < NTASK) {
        int slice = b >> 1, part = b & 1;
        int lo = part * PART_N;
        for (int k = t; k < PART_N / 2; k += 256) hist[k] = 0;
        __syncthreads();
        int e0 = slice * SLICE_E;
        for (int k = t; k < SLICE_E; k += 256) {
            int e = e0 + k;
            int d = dst[e];
            unsigned dl = (unsigned)(d - lo);
            if (dl < (unsigned)PART_N) {
                unsigned old = atomicAdd(&hist[dl >> 1], (dl & 1) ? 65536u : 1u);
                rank[e] = (unsigned short)((old >> ((dl & 1) << 4)) & 0xffffu);
            }
        }
        __syncthreads();
        for (int k = t; k < PART_N; k += 256)
            arr[(size_t)slice * N_NODES + lo + k] =
                (hist[k >> 1] >> ((k & 1) << 4)) & 0xffffu;
    } else {
        int cb = b - NTASK;                     // 0..511
        for (int g = cb * 256 + t; g < 800000; g += CVT_B * 256) {
            float4 v0 = *(const float4*)(x + (size_t)g * 8);
            float4 v1 = *(const float4*)(x + (size_t)g * 8 + 4);
            uint4 o;
            o.x = f2b(v0.x) | (f2b(v0.y) << 16);
            o.y = f2b(v0.z) | (f2b(v0.w) << 16);
            o.z = f2b(v1.x) | (f2b(v1.y) << 16);
            o.w = f2b(v1.z) | (f2b(v1.w) << 16);
            int d = g >> 4;
            int j = (g & 15) << 2;
            *(uint4*)(xb + (size_t)d * 64 + j) = o;
        }
        for (int tt = cb * 256 + t; tt < 65536; tt += CVT_B * 256) {
            int j = tt & 7;
            int lane = (tt >> 3) & 63;
            int ks = (tt >> 9) & 7;
            int nt = tt >> 12;
            int k = ks * 32 + ((lane >> 4) << 3) + j;
            int n = (nt << 4) + (lane & 15);
            float v = (k < 128) ? W1l[k * 256 + n] : W1r[(k - 128) * 256 + n];
            Wfrag[tt] = (unsigned short)f2b(v);
        }
    }
}

// ---------- CSR step B: cnt[d] = sum over slices; per-block sums for scan ----
__global__ void scan1(const unsigned* __restrict__ arr, int* __restrict__ cnt,
                      int* __restrict__ bsum) {
    __shared__ int tmp[256];
    int t = threadIdx.x;
    int i = blockIdx.x * 256 + t;
    int c = 0;
    if (i < N_NODES) {
#pragma unroll 8
        for (int k = 0; k < NSLICE; k++) c += (int)arr[(size_t)k * N_NODES + i];
        cnt[i] = c;
    }
    tmp[t] = c;
    __syncthreads();
    for (int off = 128; off > 0; off >>= 1) {
        if (t < off) tmp[t] += tmp[t + off];
        __syncthreads();
    }
    if (t == 0) bsum[blockIdx.x] = tmp[0];
}

// ---------- CSR step C: exclusive scan -> rowbeg, fused per-slice offset prefix ----
__global__ void scanB(const int* __restrict__ cnt, const int* __restrict__ bsum,
                      int* __restrict__ rowbeg, unsigned* __restrict__ arr) {
    __shared__ int bs[256];
    __shared__ int tmp[256];
    int t = threadIdx.x;
    int b = blockIdx.x;
    bs[t] = (t < NB_SCAN) ? bsum[t] : 0;
    __syncthreads();
    for (int off = 1; off < 256; off <<= 1) {
        int y = (t >= off) ? bs[t - off] : 0;
        __syncthreads();
        bs[t] += y;
        __syncthreads();
    }
    int boff = (b == 0) ? 0 : bs[b - 1];
    int i = b * 256 + t;
    int v = (i < N_NODES) ? cnt[i] : 0;
    tmp[t] = v;
    __syncthreads();
    for (int off = 1; off < 256; off <<= 1) {
        int y = (t >= off) ? tmp[t - off] : 0;
        __syncthreads();
        tmp[t] += y;
        __syncthreads();
    }
    if (i < N_NODES) {
        unsigned running = (unsigned)(tmp[t] - v + boff);
        rowbeg[i] = (int)running;
        // fused offs: arr[k][i] <- global base for (slice k, node i)
#pragma unroll 8
        for (int k = 0; k < NSLICE; k++) {
            unsigned old = arr[(size_t)k * N_NODES + i];
            arr[(size_t)k * N_NODES + i] = running;
            running += old;
        }
    }
}

// ---------- CSR step D: edge-parallel scatter via precomputed ranks ----------
__global__ __launch_bounds__(256) void scatter2(
    const int* __restrict__ src, const int* __restrict__ dst,
    const unsigned* __restrict__ arr, const unsigned short* __restrict__ rank,
    unsigned short* __restrict__ esrc) {
    int e = blockIdx.x * 256 + threadIdx.x;
    if (e < N_EDGES) {
        int slice = e / SLICE_E;               // magic-mul by compiler
        int d = dst[e];
        unsigned pos = arr[(size_t)slice * N_NODES + d] + (unsigned)rank[e];
        esrc[pos] = (unsigned short)src[e];
    }
}

// ---------- agg1: wave-per-node, uint4 gather (4 edges/iter, 16 lanes/row) ----
__global__ __launch_bounds__(256) void agg1(
    const unsigned* __restrict__ xb, unsigned* __restrict__ mb,
    const unsigned short* __restrict__ esrc,
    const int* __restrict__ rowbeg, const int* __restrict__ cnt) {
    int wid = (blockIdx.x * 256 + threadIdx.x) >> 6;   // 8192 waves
    int lane = threadIdx.x & 63;
    int g = lane >> 4;
    int i = lane & 15;
    for (int d = wid; d < N_NODES; d += AGG_B * 4) {
        int beg = rowbeg[d];
        int c = cnt[d];
        int end = beg + c;
        float acc[8];
#pragma unroll
        for (int f = 0; f < 8; f++) acc[f] = 0.0f;

        for (int base = beg; base < end; base += 64) {
            int m = end - base; if (m > 64) m = 64;
            int idx = base + lane;
            int e = (int)esrc[idx < end ? idx : end - 1];  // coalesced, clamped
            for (int j0 = 0; j0 < m; j0 += 4) {
                int ss = __shfl(e, j0 + g);                // per-lane src (bpermute)
                float sc = (j0 + g < m) ? 1.0f : 0.0f;
                uint4 u = *(const uint4*)(xb + (size_t)ss * 64 + (i << 2));
                acc[0] += sc * __builtin_bit_cast(float, u.x << 16);
                acc[1] += sc * __builtin_bit_cast(float, u.x & 0xffff0000u);
                acc[2] += sc * __builtin_bit_cast(float, u.y << 16);
                acc[3] += sc * __builtin_bit_cast(float, u.y & 0xffff0000u);
                acc[4] += sc * __builtin_bit_cast(float, u.z << 16);
                acc[5] += sc * __builtin_bit_cast(float, u.z & 0xffff0000u);
                acc[6] += sc * __builtin_bit_cast(float, u.w << 16);
                acc[7] += sc * __builtin_bit_cast(float, u.w & 0xffff0000u);
            }
        }
        // combine the 4 edge-groups: lanes {i, i+16, i+32, i+48}
#pragma unroll
        for (int f = 0; f < 8; f++) {
            acc[f] += __shfl_xor(acc[f], 16);
            acc[f] += __shfl_xor(acc[f], 32);
        }
        if (lane < 16) {
            float inv = 1.0f / fmaxf((float)c, 1.0f);
            uint4 o;
            o.x = f2b(acc[0] * inv) | (f2b(acc[1] * inv) << 16);
            o.y = f2b(acc[2] * inv) | (f2b(acc[3] * inv) << 16);
            o.z = f2b(acc[4] * inv) | (f2b(acc[5] * inv) << 16);
            o.w = f2b(acc[6] * inv) | (f2b(acc[7] * inv) << 16);
            *(uint4*)(mb + (size_t)d * 64 + (i << 2)) = o;
        }
    }
}

// ---------- gemm1 + fused ps (M=64): h = relu([mean|x]@Wcat + b1); p,s = h@W2 ----
// 64 rows/block, 256 threads (4 waves); wave w owns cols w*64..w*64+63.
__global__ __launch_bounds__(256) void gemm1ps(
    const unsigned* __restrict__ mb, const unsigned* __restrict__ xb,
    const unsigned short* __restrict__ Wfrag, const float* __restrict__ b1,
    const float* __restrict__ W2l, const float* __restrict__ W2r,
    const float* __restrict__ b2,
    float* __restrict__ h, float* __restrict__ p, float* __restrict__ s) {
    __shared__ unsigned A[64 * 128];   // 32 KB, 16B-chunk XOR swizzled (k0-127: mean|x)
    __shared__ float ppart[64][4];     // p0,p1,s0,s1 partials per row

    int r0 = blockIdx.x * 64;
    int tid = threadIdx.x;
    int w = tid >> 6;          // 0..3
    int lane = tid & 63;
    int quad = lane >> 4;
    int l15 = lane & 15;

    ((float*)ppart)[tid] = 0.0f;       // 256 = 64*4 exactly

    int sr = tid >> 3;                 // 0..31
    int c0 = tid & 7;
#pragma unroll
    for (int jj = 0; jj < 2; jj++) {
        int row = (jj << 5) + sr;      // 0..63
#pragma unroll
        for (int j = 0; j < 4; j++) {
            int c = c0 + (j << 3);     // 0..31
            uint4 v;
            if (c < 16) v = *(const uint4*)(mb + (size_t)(r0 + row) * 64 + (c << 2));
            else        v = *(const uint4*)(xb + (size_t)(r0 + row) * 64 + ((c - 16) << 2));
            int cp = c ^ (row & 7);
            *(uint4*)(A + row * 128 + (cp << 2)) = v;
        }
    }
    __syncthreads();

    f32x4 acc[16];
#pragma unroll
    for (int i = 0; i < 16; i++) acc[i] = (f32x4){0.0f, 0.0f, 0.0f, 0.0f};

    for (int ks = 0; ks < 8; ks++) {
        bf16x8 bfr[4];
#pragma unroll
        for (int nt = 0; nt < 4; nt++) {
            int ntg = (w << 2) + nt;
            uint4 raw = *(const uint4*)(Wfrag + ((((ntg << 3) + ks) << 6) + lane) * 8);
            bfr[nt] = __builtin_bit_cast(bf16x8, raw);
        }
#pragma unroll
        for (int mt = 0; mt < 4; mt++) {
            int row = (mt << 4) + l15;
            int c = (ks << 2) + quad;
            uint4 araw = *(const uint4*)(A + row * 128 + ((c ^ (row & 7)) << 2));
            bf16x8 afr = __builtin_bit_cast(bf16x8, araw);
#pragma unroll
            for (int nt = 0; nt < 4; nt++) {
                acc[(mt << 2) + nt] = __builtin_amdgcn_mfma_f32_16x16x32_bf16(
                    afr, bfr[nt], acc[(mt << 2) + nt], 0, 0, 0);
            }
        }
    }

    float w2[4][4];
#pragma unroll
    for (int nt = 0; nt < 4; nt++) {
        int col = (w << 6) + (nt << 4) + l15;
        float2 l2 = *(const float2*)(W2l + col * 2);
        float2 r2 = *(const float2*)(W2r + col * 2);
        w2[nt][0] = l2.x; w2[nt][1] = l2.y; w2[nt][2] = r2.x; w2[nt][3] = r2.y;
    }

#pragma unroll
    for (int mt = 0; mt < 4; mt++) {
        float red[4][4];
#pragma unroll
        for (int v = 0; v < 4; v++)
#pragma unroll
            for (int r = 0; r < 4; r++) red[v][r] = 0.0f;

#pragma unroll
        for (int nt = 0; nt < 4; nt++) {
            int col = (w << 6) + (nt << 4) + l15;
            float b = b1[col];
            f32x4 v = acc[(mt << 2) + nt];
#pragma unroll
            for (int r = 0; r < 4; r++) {
                float hv = v[r] + b;
                hv = hv > 0.0f ? hv : 0.0f;
                int row = r0 + (mt << 4) + (quad << 2) + r;
                if (row < N_NODES)
                    __builtin_nontemporal_store(hv, &h[(size_t)row * 256 + col]);
                red[0][r] += hv * w2[nt][0];
                red[1][r] += hv * w2[nt][1];
                red[2][r] += hv * w2[nt][2];
                red[3][r] += hv * w2[nt][3];
            }
        }
#pragma unroll
        for (int v = 0; v < 4; v++)
#pragma unroll
            for (int r = 0; r < 4; r++) {
                red[v][r] += __shfl_xor(red[v][r], 1);
                red[v][r] += __shfl_xor(red[v][r], 2);
                red[v][r] += __shfl_xor(red[v][r], 4);
                red[v][r] += __shfl_xor(red[v][r], 8);
            }
        if (l15 == 0) {
            int lrow = (mt << 4) + (quad << 2);
#pragma unroll
            for (int r = 0; r < 4; r++)
#pragma unroll
                for (int v = 0; v < 4; v++)
                    atomicAdd(&ppart[lrow + r][v], red[v][r]);
        }
    }
    __syncthreads();

    if (tid < 64) {
        int row = r0 + tid;
        if (row < N_NODES) {
            float2 pv = {ppart[tid][0], ppart[tid][1]};
            float2 sv = {ppart[tid][2] + b2[0], ppart[tid][3] + b2[1]};
            *(float2*)(p + (size_t)row * 2) = pv;
            *(float2*)(s + (size_t)row * 2) = sv;
        }
    }
}

// ---------- layer-2: wave-per-node grid-stride, gather-mean of p + sigmoid ----
__global__ __launch_bounds__(256) void agg2(
    const float* __restrict__ p, const float* __restrict__ s,
    const unsigned short* __restrict__ esrc,
    const int* __restrict__ rowbeg, const int* __restrict__ cnt,
    float* __restrict__ out) {
    int wid = (blockIdx.x * 256 + threadIdx.x) >> 6;
    int lane = threadIdx.x & 63;
    for (int d = wid; d < N_NODES; d += AGG_B * 4) {
        int beg = rowbeg[d];
        int c = cnt[d];
        int end = beg + c;
        float a0 = 0.0f, a1 = 0.0f;
        for (int base = beg; base < end; base += 64) {
            int idx = base + lane;
            if (idx < end) {
                int ss = (int)esrc[idx];
                float2 v = *(const float2*)(p + (size_t)ss * 2);
                a0 += v.x; a1 += v.y;
            }
        }
#pragma unroll
        for (int off = 32; off > 0; off >>= 1) {
            a0 += __shfl_down(a0, off);
            a1 += __shfl_down(a1, off);
        }
        if (lane == 0) {
            float inv = 1.0f / fmaxf((float)c, 1.0f);
            float z0 = a0 * inv + s[(size_t)d * 2 + 0];
            float z1 = a1 * inv + s[(size_t)d * 2 + 1];
            float2 o = {1.0f / (1.0f + expf(-z0)), 1.0f / (1.0f + expf(-z1))};
            *(float2*)(out + (size_t)d * 2) = o;
        }
    }
}

extern "C" void kernel_launch(void* const* d_in, const int* in_sizes, int n_in,
                              void* d_out, int out_size, void* d_ws, size_t ws_size,
                              hipStream_t stream) {
    const float* x   = (const float*)d_in[0];
    const int*   ei  = (const int*)d_in[1];
    const float* W1l = (const float*)d_in[2];
    const float* W1r = (const float*)d_in[3];
    const float* b1  = (const float*)d_in[4];
    const float* W2l = (const float*)d_in[5];
    const float* W2r = (const float*)d_in[6];
    const float* b2  = (const float*)d_in[7];

    const int* src = ei;
    const int* dst = ei + N_EDGES;

    float* out = (float*)d_out;               // [50000, 2]
    float* emb = out + (size_t)N_NODES * 2;   // [50000, 256] == h

    // ---- workspace layout; arr (6.4 MB) aliases mb (dead after scatter) ----
    int* cnt    = (int*)d_ws;                             // 50000
    int* rowbeg = cnt + N_NODES;                          // 50000
    int* bsum   = rowbeg + N_NODES;                       // 256
    unsigned short* esrc = (unsigned short*)(bsum + 256); // 800064 (16B-mult pad)
    unsigned* xb = (unsigned*)(esrc + 800064);            // 50048 x 64 uints
    unsigned* mb = xb + (size_t)50048 * 64;               // 50048 x 64 uints
    unsigned* arr = mb;                                   // 32 x 50000 uints (alias)
    unsigned short* Wfrag = (unsigned short*)(mb + (size_t)50048 * 64);  // 65536
    float* p = (float*)(Wfrag + 65536);                   // 100000
    float* s = p + (size_t)N_NODES * 2;                   // 100000
    // rank lives in the emb output region: dead until gemm1ps writes h (after scatter)
    unsigned short* rank = (unsigned short*)emb;          // 800000 u16 = 1.6 MB

    prep_hist<<<PH_B, 256, 0, stream>>>(x, dst, W1l, W1r, arr, rank, xb, Wfrag);
    scan1<<<NB_SCAN, 256, 0, stream>>>(arr, cnt, bsum);
    scanB<<<NB_SCAN, 256, 0, stream>>>(cnt, bsum, rowbeg, arr);
    scatter2<<<SCAT_B, 256, 0, stream>>>(src, dst, arr, rank, esrc);

    agg1<<<AGG_B, 256, 0, stream>>>(xb, mb, esrc, rowbeg, cnt);

    gemm1ps<<<GEMM_BLOCKS, 256, 0, stream>>>(mb, xb, Wfrag, b1, W2l, W2r, b2,
                                             emb, p, s);

    agg2<<<AGG_B, 256, 0, stream>>>(p, s, esrc, rowbeg, cnt, out);
}

// Round 4
// 215.512 us; speedup vs baseline: 1.0541x; 1.0541x over previous
//
#include <hip/hip_runtime.h>
#include <math.h>

#define N_NODES 50000
#define N_EDGES 800000
#define D_FEAT 128
#define HIDDEN 256
#define NB_SCAN 196           // ceil(50000/256)
#define GEMM_BLOCKS 782       // ceil(50000/64)

#define AGG_B 2048            // 8192 waves

#define CVT_B 512             // cvt/Wfrag blocks in count_prep
#define CNT_B 3125            // 800000/256 edge-parallel count blocks
#define CP_B (CVT_B + CNT_B)
#define SCAT_B 3125           // 800000/256 edge-parallel scatter

typedef __bf16 bf16x8 __attribute__((ext_vector_type(8)));
typedef float f32x4 __attribute__((ext_vector_type(4)));

__device__ __forceinline__ unsigned f2b(float f) {
    unsigned u = __builtin_bit_cast(unsigned, f);
    return (u + 0x7fff + ((u >> 16) & 1)) >> 16;  // RNE, low 16 bits valid
}

// ---------- fused: cvt_x | build_wfrag | edge count + rank (global atomics) ----
// blocks 0..511: x -> bf16-packed xb, W1l|W1r -> MFMA-layout Wfrag.
// blocks 512..3636: rank[e] = old count of dst[e] (unique slot in node's list).
__global__ __launch_bounds__(256) void count_prep(
    const float* __restrict__ x, const int* __restrict__ dst,
    const float* __restrict__ W1l, const float* __restrict__ W1r,
    int* __restrict__ cnt, unsigned short* __restrict__ rank,
    unsigned* __restrict__ xb, unsigned short* __restrict__ Wfrag) {
    int b = blockIdx.x;
    int t = threadIdx.x;
    if (b < CVT_B) {
        for (int g = b * 256 + t; g < 800000; g += CVT_B * 256) {
            float4 v0 = *(const float4*)(x + (size_t)g * 8);
            float4 v1 = *(const float4*)(x + (size_t)g * 8 + 4);
            uint4 o;
            o.x = f2b(v0.x) | (f2b(v0.y) << 16);
            o.y = f2b(v0.z) | (f2b(v0.w) << 16);
            o.z = f2b(v1.x) | (f2b(v1.y) << 16);
            o.w = f2b(v1.z) | (f2b(v1.w) << 16);
            int d = g >> 4;
            int j = (g & 15) << 2;
            *(uint4*)(xb + (size_t)d * 64 + j) = o;
        }
        for (int tt = b * 256 + t; tt < 65536; tt += CVT_B * 256) {
            int j = tt & 7;
            int lane = (tt >> 3) & 63;
            int ks = (tt >> 9) & 7;
            int nt = tt >> 12;
            int k = ks * 32 + ((lane >> 4) << 3) + j;
            int n = (nt << 4) + (lane & 15);
            float v = (k < 128) ? W1l[k * 256 + n] : W1r[(k - 128) * 256 + n];
            Wfrag[tt] = (unsigned short)f2b(v);
        }
    } else {
        int e = (b - CVT_B) * 256 + t;
        if (e < N_EDGES) {
            int d = dst[e];
            rank[e] = (unsigned short)atomicAdd(&cnt[d], 1);
        }
    }
}

// ---------- scan step A: per-block sums of cnt ----------
__global__ void scan1(const int* __restrict__ cnt, int* __restrict__ bsum) {
    __shared__ int tmp[256];
    int t = threadIdx.x;
    int i = blockIdx.x * 256 + t;
    int c = (i < N_NODES) ? cnt[i] : 0;
    tmp[t] = c;
    __syncthreads();
    for (int off = 128; off > 0; off >>= 1) {
        if (t < off) tmp[t] += tmp[t + off];
        __syncthreads();
    }
    if (t == 0) bsum[blockIdx.x] = tmp[0];
}

// ---------- scan step B: exclusive scan -> rowbeg ----------
__global__ void scanB(const int* __restrict__ cnt, const int* __restrict__ bsum,
                      int* __restrict__ rowbeg) {
    __shared__ int bs[256];
    __shared__ int tmp[256];
    int t = threadIdx.x;
    int b = blockIdx.x;
    bs[t] = (t < NB_SCAN) ? bsum[t] : 0;
    __syncthreads();
    for (int off = 1; off < 256; off <<= 1) {
        int y = (t >= off) ? bs[t - off] : 0;
        __syncthreads();
        bs[t] += y;
        __syncthreads();
    }
    int boff = (b == 0) ? 0 : bs[b - 1];
    int i = b * 256 + t;
    int v = (i < N_NODES) ? cnt[i] : 0;
    tmp[t] = v;
    __syncthreads();
    for (int off = 1; off < 256; off <<= 1) {
        int y = (t >= off) ? tmp[t - off] : 0;
        __syncthreads();
        tmp[t] += y;
        __syncthreads();
    }
    if (i < N_NODES) rowbeg[i] = tmp[t] - v + boff;
}

// ---------- scatter: esrc[rowbeg[dst] + rank] = src, edge-parallel ----------
__global__ __launch_bounds__(256) void scatter2(
    const int* __restrict__ src, const int* __restrict__ dst,
    const int* __restrict__ rowbeg, const unsigned short* __restrict__ rank,
    unsigned short* __restrict__ esrc) {
    int e = blockIdx.x * 256 + threadIdx.x;
    if (e < N_EDGES) {
        int d = dst[e];
        unsigned pos = (unsigned)rowbeg[d] + (unsigned)rank[e];
        esrc[pos] = (unsigned short)src[e];
    }
}

// ---------- agg1: wave-per-node, uint4 gather (4 edges/iter, 16 lanes/row) ----
__global__ __launch_bounds__(256) void agg1(
    const unsigned* __restrict__ xb, unsigned* __restrict__ mb,
    const unsigned short* __restrict__ esrc,
    const int* __restrict__ rowbeg, const int* __restrict__ cnt) {
    int wid = (blockIdx.x * 256 + threadIdx.x) >> 6;   // 8192 waves
    int lane = threadIdx.x & 63;
    int g = lane >> 4;
    int i = lane & 15;
    for (int d = wid; d < N_NODES; d += AGG_B * 4) {
        int beg = rowbeg[d];
        int c = cnt[d];
        int end = beg + c;
        float acc[8];
#pragma unroll
        for (int f = 0; f < 8; f++) acc[f] = 0.0f;

        for (int base = beg; base < end; base += 64) {
            int m = end - base; if (m > 64) m = 64;
            int idx = base + lane;
            int e = (int)esrc[idx < end ? idx : end - 1];  // coalesced, clamped
            for (int j0 = 0; j0 < m; j0 += 4) {
                int ss = __shfl(e, j0 + g);                // per-lane src (bpermute)
                float sc = (j0 + g < m) ? 1.0f : 0.0f;
                uint4 u = *(const uint4*)(xb + (size_t)ss * 64 + (i << 2));
                acc[0] += sc * __builtin_bit_cast(float, u.x << 16);
                acc[1] += sc * __builtin_bit_cast(float, u.x & 0xffff0000u);
                acc[2] += sc * __builtin_bit_cast(float, u.y << 16);
                acc[3] += sc * __builtin_bit_cast(float, u.y & 0xffff0000u);
                acc[4] += sc * __builtin_bit_cast(float, u.z << 16);
                acc[5] += sc * __builtin_bit_cast(float, u.z & 0xffff0000u);
                acc[6] += sc * __builtin_bit_cast(float, u.w << 16);
                acc[7] += sc * __builtin_bit_cast(float, u.w & 0xffff0000u);
            }
        }
        // combine the 4 edge-groups: lanes {i, i+16, i+32, i+48}
#pragma unroll
        for (int f = 0; f < 8; f++) {
            acc[f] += __shfl_xor(acc[f], 16);
            acc[f] += __shfl_xor(acc[f], 32);
        }
        if (lane < 16) {
            float inv = 1.0f / fmaxf((float)c, 1.0f);
            uint4 o;
            o.x = f2b(acc[0] * inv) | (f2b(acc[1] * inv) << 16);
            o.y = f2b(acc[2] * inv) | (f2b(acc[3] * inv) << 16);
            o.z = f2b(acc[4] * inv) | (f2b(acc[5] * inv) << 16);
            o.w = f2b(acc[6] * inv) | (f2b(acc[7] * inv) << 16);
            *(uint4*)(mb + (size_t)d * 64 + (i << 2)) = o;
        }
    }
}

// ---------- gemm1 + fused ps (M=64): h = relu([mean|x]@Wcat + b1); p,s = h@W2 ----
// 64 rows/block, 256 threads (4 waves); wave w owns cols w*64..w*64+63.
__global__ __launch_bounds__(256) void gemm1ps(
    const unsigned* __restrict__ mb, const unsigned* __restrict__ xb,
    const unsigned short* __restrict__ Wfrag, const float* __restrict__ b1,
    const float* __restrict__ W2l, const float* __restrict__ W2r,
    const float* __restrict__ b2,
    float* __restrict__ h, float* __restrict__ p, float* __restrict__ s) {
    __shared__ unsigned A[64 * 128];   // 32 KB, 16B-chunk XOR swizzled (k0-127: mean|x)
    __shared__ float ppart[64][4];     // p0,p1,s0,s1 partials per row

    int r0 = blockIdx.x * 64;
    int tid = threadIdx.x;
    int w = tid >> 6;          // 0..3
    int lane = tid & 63;
    int quad = lane >> 4;
    int l15 = lane & 15;

    ((float*)ppart)[tid] = 0.0f;       // 256 = 64*4 exactly

    int sr = tid >> 3;                 // 0..31
    int c0 = tid & 7;
#pragma unroll
    for (int jj = 0; jj < 2; jj++) {
        int row = (jj << 5) + sr;      // 0..63
#pragma unroll
        for (int j = 0; j < 4; j++) {
            int c = c0 + (j << 3);     // 0..31
            uint4 v;
            if (c < 16) v = *(const uint4*)(mb + (size_t)(r0 + row) * 64 + (c << 2));
            else        v = *(const uint4*)(xb + (size_t)(r0 + row) * 64 + ((c - 16) << 2));
            int cp = c ^ (row & 7);
            *(uint4*)(A + row * 128 + (cp << 2)) = v;
        }
    }
    __syncthreads();

    f32x4 acc[16];
#pragma unroll
    for (int i = 0; i < 16; i++) acc[i] = (f32x4){0.0f, 0.0f, 0.0f, 0.0f};

    for (int ks = 0; ks < 8; ks++) {
        bf16x8 bfr[4];
#pragma unroll
        for (int nt = 0; nt < 4; nt++) {
            int ntg = (w << 2) + nt;
            uint4 raw = *(const uint4*)(Wfrag + ((((ntg << 3) + ks) << 6) + lane) * 8);
            bfr[nt] = __builtin_bit_cast(bf16x8, raw);
        }
#pragma unroll
        for (int mt = 0; mt < 4; mt++) {
            int row = (mt << 4) + l15;
            int c = (ks << 2) + quad;
            uint4 araw = *(const uint4*)(A + row * 128 + ((c ^ (row & 7)) << 2));
            bf16x8 afr = __builtin_bit_cast(bf16x8, araw);
#pragma unroll
            for (int nt = 0; nt < 4; nt++) {
                acc[(mt << 2) + nt] = __builtin_amdgcn_mfma_f32_16x16x32_bf16(
                    afr, bfr[nt], acc[(mt << 2) + nt], 0, 0, 0);
            }
        }
    }

    float w2[4][4];
#pragma unroll
    for (int nt = 0; nt < 4; nt++) {
        int col = (w << 6) + (nt << 4) + l15;
        float2 l2 = *(const float2*)(W2l + col * 2);
        float2 r2 = *(const float2*)(W2r + col * 2);
        w2[nt][0] = l2.x; w2[nt][1] = l2.y; w2[nt][2] = r2.x; w2[nt][3] = r2.y;
    }

#pragma unroll
    for (int mt = 0; mt < 4; mt++) {
        float red[4][4];
#pragma unroll
        for (int v = 0; v < 4; v++)
#pragma unroll
            for (int r = 0; r < 4; r++) red[v][r] = 0.0f;

#pragma unroll
        for (int nt = 0; nt < 4; nt++) {
            int col = (w << 6) + (nt << 4) + l15;
            float b = b1[col];
            f32x4 v = acc[(mt << 2) + nt];
#pragma unroll
            for (int r = 0; r < 4; r++) {
                float hv = v[r] + b;
                hv = hv > 0.0f ? hv : 0.0f;
                int row = r0 + (mt << 4) + (quad << 2) + r;
                if (row < N_NODES)
                    __builtin_nontemporal_store(hv, &h[(size_t)row * 256 + col]);
                red[0][r] += hv * w2[nt][0];
                red[1][r] += hv * w2[nt][1];
                red[2][r] += hv * w2[nt][2];
                red[3][r] += hv * w2[nt][3];
            }
        }
#pragma unroll
        for (int v = 0; v < 4; v++)
#pragma unroll
            for (int r = 0; r < 4; r++) {
                red[v][r] += __shfl_xor(red[v][r], 1);
                red[v][r] += __shfl_xor(red[v][r], 2);
                red[v][r] += __shfl_xor(red[v][r], 4);
                red[v][r] += __shfl_xor(red[v][r], 8);
            }
        if (l15 == 0) {
            int lrow = (mt << 4) + (quad << 2);
#pragma unroll
            for (int r = 0; r < 4; r++)
#pragma unroll
                for (int v = 0; v < 4; v++)
                    atomicAdd(&ppart[lrow + r][v], red[v][r]);
        }
    }
    __syncthreads();

    if (tid < 64) {
        int row = r0 + tid;
        if (row < N_NODES) {
            float2 pv = {ppart[tid][0], ppart[tid][1]};
            float2 sv = {ppart[tid][2] + b2[0], ppart[tid][3] + b2[1]};
            *(float2*)(p + (size_t)row * 2) = pv;
            *(float2*)(s + (size_t)row * 2) = sv;
        }
    }
}

// ---------- layer-2: wave-per-node grid-stride, gather-mean of p + sigmoid ----
__global__ __launch_bounds__(256) void agg2(
    const float* __restrict__ p, const float* __restrict__ s,
    const unsigned short* __restrict__ esrc,
    const int* __restrict__ rowbeg, const int* __restrict__ cnt,
    float* __restrict__ out) {
    int wid = (blockIdx.x * 256 + threadIdx.x) >> 6;
    int lane = threadIdx.x & 63;
    for (int d = wid; d < N_NODES; d += AGG_B * 4) {
        int beg = rowbeg[d];
        int c = cnt[d];
        int end = beg + c;
        float a0 = 0.0f, a1 = 0.0f;
        for (int base = beg; base < end; base += 64) {
            int idx = base + lane;
            if (idx < end) {
                int ss = (int)esrc[idx];
                float2 v = *(const float2*)(p + (size_t)ss * 2);
                a0 += v.x; a1 += v.y;
            }
        }
#pragma unroll
        for (int off = 32; off > 0; off >>= 1) {
            a0 += __shfl_down(a0, off);
            a1 += __shfl_down(a1, off);
        }
        if (lane == 0) {
            float inv = 1.0f / fmaxf((float)c, 1.0f);
            float z0 = a0 * inv + s[(size_t)d * 2 + 0];
            float z1 = a1 * inv + s[(size_t)d * 2 + 1];
            float2 o = {1.0f / (1.0f + expf(-z0)), 1.0f / (1.0f + expf(-z1))};
            *(float2*)(out + (size_t)d * 2) = o;
        }
    }
}

extern "C" void kernel_launch(void* const* d_in, const int* in_sizes, int n_in,
                              void* d_out, int out_size, void* d_ws, size_t ws_size,
                              hipStream_t stream) {
    const float* x   = (const float*)d_in[0];
    const int*   ei  = (const int*)d_in[1];
    const float* W1l = (const float*)d_in[2];
    const float* W1r = (const float*)d_in[3];
    const float* b1  = (const float*)d_in[4];
    const float* W2l = (const float*)d_in[5];
    const float* W2r = (const float*)d_in[6];
    const float* b2  = (const float*)d_in[7];

    const int* src = ei;
    const int* dst = ei + N_EDGES;

    float* out = (float*)d_out;               // [50000, 2]
    float* emb = out + (size_t)N_NODES * 2;   // [50000, 256] == h

    // ---- workspace layout (~28 MB) ----
    int* cnt    = (int*)d_ws;                             // 50000
    int* rowbeg = cnt + N_NODES;                          // 50000
    int* bsum   = rowbeg + N_NODES;                       // 256
    unsigned short* esrc = (unsigned short*)(bsum + 256); // 800064 (16B-mult pad)
    unsigned* xb = (unsigned*)(esrc + 800064);            // 50048 x 64 uints
    unsigned* mb = xb + (size_t)50048 * 64;               // 50048 x 64 uints
    unsigned short* Wfrag = (unsigned short*)(mb + (size_t)50048 * 64);  // 65536
    float* p = (float*)(Wfrag + 65536);                   // 100000
    float* s = p + (size_t)N_NODES * 2;                   // 100000
    // rank lives in the emb output region: dead until gemm1ps writes h (after scatter)
    unsigned short* rank = (unsigned short*)emb;          // 800000 u16 = 1.6 MB

    hipMemsetAsync(cnt, 0, N_NODES * sizeof(int), stream);

    count_prep<<<CP_B, 256, 0, stream>>>(x, dst, W1l, W1r, cnt, rank, xb, Wfrag);
    scan1<<<NB_SCAN, 256, 0, stream>>>(cnt, bsum);
    scanB<<<NB_SCAN, 256, 0, stream>>>(cnt, bsum, rowbeg);
    scatter2<<<SCAT_B, 256, 0, stream>>>(src, dst, rowbeg, rank, esrc);

    agg1<<<AGG_B, 256, 0, stream>>>(xb, mb, esrc, rowbeg, cnt);

    gemm1ps<<<GEMM_BLOCKS, 256, 0, stream>>>(mb, xb, Wfrag, b1, W2l, W2r, b2,
                                             emb, p, s);

    agg2<<<AGG_B, 256, 0, stream>>>(p, s, esrc, rowbeg, cnt, out);
}